// Round 1
// baseline (153.702 us; speedup 1.0000x reference)
//
#include <hip/hip_runtime.h>

// Problem constants (B, L, NSESS, S, H) = (16, 512, 4, 512, 512)
constexpr int B     = 16;
constexpr int L     = 512;
constexpr int NSESS = 4;
constexpr int S     = 512;
constexpr int H     = 512;
constexpr int HV    = H / 4;   // 128 float4 per row

// Native vector type for non-temporal stores (__builtin_nontemporal_store
// requires a scalar/vector type; HIP's float4 is a struct).
typedef float v4f __attribute__((ext_vector_type(4)));

// One block per (b, l). 128 threads: lane j handles float4 column j of all
// 5 gathered rows. Rows are 2 KB contiguous -> fully coalesced loads/stores.
//
// XCD-aware bijective swizzle (8192 blocks, 8 XCDs, 8192 % 8 == 0):
//   bl = (orig % 8) * 1024 + orig / 8
// XCD x (blocks with orig % 8 == x under round-robin dispatch) gets the
// contiguous work range [x*1024, x*1024+1023] = b = 2x then b = 2x+1, walked
// in l-order. Temporal read working set per XCD = one b's session tile
// (4*512*512*4 B = 4 MiB) ~= the per-XCD L2 (4 MiB), so the 1.25x row reuse
// and the p0/p4 session-3 double-touch become L2 hits instead of LLC/HBM.
//
// Output is never re-read: non-temporal (evict-first) stores keep the 84 MB
// write stream from thrashing the session rows out of L2.
__global__ __launch_bounds__(128)
void state_matrix_encoder_kernel(const float* __restrict__ sess_repre,
                                 const int*   __restrict__ stm,
                                 float*       __restrict__ out)
{
    const int orig = blockIdx.x;                       // 0 .. B*L-1
    const int bl   = (orig & 7) * (B * L / 8) + (orig >> 3);
    const int b    = bl >> 9;                          // bl / L   (L = 512)
    const int j    = threadIdx.x;                      // float4 column, 0..127

    // 5 indices for this (b, l); uniform across the block (scalar loads)
    const int* stm_bl = stm + bl * 5;
    const int p0 = stm_bl[0] - 1;     // session 3
    const int p1 = stm_bl[1] - 1;     // session 0
    const int p2 = stm_bl[2] - 1;     // session 1
    const int p3 = stm_bl[3] - 1;     // session 2
    const int p4 = stm_bl[4] - 1;     // session 3

    const float4* base = (const float4*)sess_repre
                       + (size_t)b * (size_t)(NSESS * S * HV);

    const float4 v0 = base[(size_t)(3 * S + p0) * HV + j];
    const float4 v1 = base[(size_t)(0 * S + p1) * HV + j];
    const float4 v2 = base[(size_t)(1 * S + p2) * HV + j];
    const float4 v3 = base[(size_t)(2 * S + p3) * HV + j];
    const float4 v4 = base[(size_t)(3 * S + p4) * HV + j];

    float4 m;
    m.x = (v0.x + v1.x + v2.x + v3.x) * 0.25f;
    m.y = (v0.y + v1.y + v2.y + v3.y) * 0.25f;
    m.z = (v0.z + v1.z + v2.z + v3.z) * 0.25f;
    m.w = (v0.w + v1.w + v2.w + v3.w) * 0.25f;

    float4* o = (float4*)out + (size_t)bl * (size_t)(5 * HV) + j;
    __builtin_nontemporal_store(*(const v4f*)&m,  (v4f*)(o + 0 * HV));
    __builtin_nontemporal_store(*(const v4f*)&v1, (v4f*)(o + 1 * HV));
    __builtin_nontemporal_store(*(const v4f*)&v2, (v4f*)(o + 2 * HV));
    __builtin_nontemporal_store(*(const v4f*)&v3, (v4f*)(o + 3 * HV));
    __builtin_nontemporal_store(*(const v4f*)&v4, (v4f*)(o + 4 * HV));
}

extern "C" void kernel_launch(void* const* d_in, const int* in_sizes, int n_in,
                              void* d_out, int out_size, void* d_ws, size_t ws_size,
                              hipStream_t stream)
{
    // Input order (setup_inputs dict order):
    //   0: utterance_repre    (B, L, H)        float32  -- unused
    //   1: conversation_repre (B, H)           float32  -- unused
    //   2: session_repre      (B, NSESS, S, H) float32
    //   3: state_transition_matrix (B, L, 5)   int (harness stages ints as int32)
    //   4: max_conversation_length scalar      int      -- == L, unused
    const float* sess_repre = (const float*)d_in[2];
    const int*   stm        = (const int*)d_in[3];
    float*       out        = (float*)d_out;

    dim3 grid(B * L);   // 8192 blocks
    dim3 block(HV);     // 128 threads
    state_matrix_encoder_kernel<<<grid, block, 0, stream>>>(sess_repre, stm, out);
}

// Round 3
// 151.337 us; speedup vs baseline: 1.0156x; 1.0156x over previous
//
#include <hip/hip_runtime.h>

// Problem constants (B, L, NSESS, S, H) = (16, 512, 4, 512, 512)
constexpr int B     = 16;
constexpr int L     = 512;
constexpr int NSESS = 4;
constexpr int S     = 512;
constexpr int H     = 512;
constexpr int HV    = H / 4;   // 128 float4 per row
constexpr int G     = 2;       // l's per block
constexpr int NUNIT = B * L / G;   // 4096 blocks

// Native vector type for non-temporal stores.
typedef float v4f __attribute__((ext_vector_type(4)));

// One block per G=2 consecutive (b,l). 128 threads: lane j handles float4
// column j. All 10 row loads (2 l's x 5 rows) are issued back-to-back before
// any use -> 160 B/lane of independent loads in flight (2x the G=1 version),
// attacking the latency/MLP hypothesis for the ~3.6 TB/s effective BW.
// The 2 l's share one contiguous 40 B stm fetch (10 ints) -> one scalar
// round-trip instead of two dependent ones per l.
//
// VGPR budget: 10 x float4 data (40) + addressing (~16) stays <= 64 so
// occupancy holds at 8 waves/SIMD.
//
// XCD swizzle kept (4096 % 8 == 0, bijective); NT stores kept (output is
// never re-read; don't let the 84 MB write stream thrash L2/LLC read set).
__global__ __launch_bounds__(128)
void state_matrix_encoder_kernel(const float* __restrict__ sess_repre,
                                 const int*   __restrict__ stm,
                                 float*       __restrict__ out)
{
    const int orig = blockIdx.x;                           // 0 .. 4095
    const int unit = (orig & 7) * (NUNIT / 8) + (orig >> 3);
    const int bl0  = unit * G;                             // first (b,l)
    const int b    = bl0 >> 9;                             // bl / L (L = 512)
    const int j    = threadIdx.x;                          // float4 col, 0..127

    // 10 contiguous indices for the two (b,l)'s; uniform -> scalar loads.
    const int* q = stm + bl0 * 5;
    int p[2 * 5];
#pragma unroll
    for (int i = 0; i < 2 * 5; ++i) p[i] = q[i] - 1;

    const float4* base = (const float4*)sess_repre
                       + (size_t)b * (size_t)(NSESS * S * HV);

    // Session for each of the 5 gathered rows: {3, 0, 1, 2, 3}.
    const int so[5] = {3, 0, 1, 2, 3};

    // Issue all 10 independent row loads before any use.
    float4 v[2 * 5];
#pragma unroll
    for (int g = 0; g < 2; ++g)
#pragma unroll
        for (int r = 0; r < 5; ++r)
            v[g * 5 + r] = base[(size_t)(so[r] * S + p[g * 5 + r]) * HV + j];

#pragma unroll
    for (int g = 0; g < 2; ++g) {
        const float4 a = v[g * 5 + 0];
        const float4 c1 = v[g * 5 + 1];
        const float4 c2 = v[g * 5 + 2];
        const float4 c3 = v[g * 5 + 3];
        const float4 c4 = v[g * 5 + 4];

        float4 m;
        m.x = (a.x + c1.x + c2.x + c3.x) * 0.25f;
        m.y = (a.y + c1.y + c2.y + c3.y) * 0.25f;
        m.z = (a.z + c1.z + c2.z + c3.z) * 0.25f;
        m.w = (a.w + c1.w + c2.w + c3.w) * 0.25f;

        float4* o = (float4*)out + (size_t)(bl0 + g) * (size_t)(5 * HV) + j;
        __builtin_nontemporal_store(*(const v4f*)&m,  (v4f*)(o + 0 * HV));
        __builtin_nontemporal_store(*(const v4f*)&c1, (v4f*)(o + 1 * HV));
        __builtin_nontemporal_store(*(const v4f*)&c2, (v4f*)(o + 2 * HV));
        __builtin_nontemporal_store(*(const v4f*)&c3, (v4f*)(o + 3 * HV));
        __builtin_nontemporal_store(*(const v4f*)&c4, (v4f*)(o + 4 * HV));
    }
}

extern "C" void kernel_launch(void* const* d_in, const int* in_sizes, int n_in,
                              void* d_out, int out_size, void* d_ws, size_t ws_size,
                              hipStream_t stream)
{
    // Input order (setup_inputs dict order):
    //   0: utterance_repre    (B, L, H)        float32  -- unused
    //   1: conversation_repre (B, H)           float32  -- unused
    //   2: session_repre      (B, NSESS, S, H) float32
    //   3: state_transition_matrix (B, L, 5)   int32 (harness stages int64 as int32)
    //   4: max_conversation_length scalar      int      -- == L, unused
    const float* sess_repre = (const float*)d_in[2];
    const int*   stm        = (const int*)d_in[3];
    float*       out        = (float*)d_out;

    dim3 grid(NUNIT);   // 4096 blocks
    dim3 block(HV);     // 128 threads
    state_matrix_encoder_kernel<<<grid, block, 0, stream>>>(sess_repre, stm, out);
}